// Round 3
// baseline (1298.204 us; speedup 1.0000x reference)
//
#include <hip/hip_runtime.h>
#include <math.h>

#ifndef M_PI
#define M_PI 3.14159265358979323846
#endif

// ---------- constants ----------
#define HH   320
#define GG   640
#define NB   8
#define PTS  512000   // 800 * 640

// ---------- helpers ----------
__device__ __forceinline__ float bessel_i0f(float x){
  if (x < 3.75f){
    float t = (x*x) * (1.0f/(3.75f*3.75f));
    return 1.0f + t*(3.5156229f + t*(3.0899424f + t*(1.2067492f +
                 t*(0.2659732f + t*(0.0360768f + t*0.0045813f)))));
  } else {
    float t = 3.75f/x;
    float p = 0.39894228f + t*(0.01328592f + t*(0.00225319f + t*(-0.00157565f +
              t*(0.00916281f + t*(-0.02057706f + t*(0.02635537f +
              t*(-0.01647633f + t*0.00392377f)))))));
    return expf(x)*rsqrtf(x)*p;
  }
}

__device__ __forceinline__ float kbw(float d, float beta, float inv_i0b){
  float q = d * 0.33333333333333f;        // 2d/W with W=6
  float u = 1.0f - q*q;
  u = fmaxf(u, 0.0f);
  return bessel_i0f(beta * sqrtf(u)) * inv_i0b;
}

// ---------- build DFT matrices ----------
// M1[x,k] = (1/sqrt(320)) * (-1)^(x+k) * exp(+2*pi*i*x*k/320)
__global__ void build_m1(float2* __restrict__ M1){
  int idx = blockIdx.x*256 + threadIdx.x;
  if (idx >= HH*HH) return;
  int x = idx / HH, k = idx - x*HH;
  int r = (x*k) % HH;
  float ang = (float)r * (6.283185307179586f/(float)HH);
  float s, c; sincosf(ang, &s, &c);
  float sg = ((x + k) & 1) ? -0.05590169943749474f : 0.05590169943749474f;
  M1[idx] = make_float2(sg*c, sg*s);
}

// W2[k,m] = exp(-2*pi*i*k*(m-160)/640)   (640 x 320)
__global__ void build_w2(float2* __restrict__ W2){
  int idx = blockIdx.x*256 + threadIdx.x;
  if (idx >= GG*HH) return;
  int k = idx / HH, m = idx - k*HH;
  int t = (k * (m - 160)) % GG; if (t < 0) t += GG;
  float ang = (float)t * (6.283185307179586f/(float)GG);
  float s, c; sincosf(ang, &s, &c);
  W2[idx] = make_float2(c, -s);
}

// rap[n] = 1 / apod1d(n)
__global__ void build_rap(float* __restrict__ rap, float beta){
  int n = threadIdx.x;  // 320 threads
  if (n >= HH) return;
  float f = (float)(n - 160) * (1.0f/(float)GG);
  float w = 3.14159265358979f * 6.0f * f;
  float t = beta*beta - w*w;
  float z = fmaxf(sqrtf(fabsf(t)), 1e-7f);
  float a = (t > 0.0f ? sinhf(z) : sinf(z)) / z;
  float a0 = sinhf(beta) / beta;
  rap[n] = a0 / a;
}

// ---------- pack two real arrays into interleaved complex ----------
__global__ void pack_c(const float* __restrict__ re, const float* __restrict__ im,
                       float2* __restrict__ out, int n){
  int i = blockIdx.x*256 + threadIdx.x;
  if (i < n) out[i] = make_float2(re[i], im[i]);
}

// ---------- batched complex GEMM ----------
// TB=0 (NN): C[i,j] = sum_k A[i,k]*B[k,j]
// TB=1 (NT): C[i,j] = sum_k A[i,k]*B[j,k]
#define BM 64
#define BN 64
#define BK 16

template<int TB>
__global__ __launch_bounds__(256)
void cgemm(const float2* __restrict__ A, int lda, long abatch,
           const float2* __restrict__ B, int ldb, long bbatch,
           float2* __restrict__ C, int ldc, long cbatch,
           int M, int N, int K)
{
  __shared__ float2 As[BM][BK+1];
  __shared__ float2 Bs[BK][BN+1];
  int b = blockIdx.z;
  A += (long)b * abatch;
  B += (long)b * bbatch;
  C += (long)b * cbatch;
  int i0 = blockIdx.y * BM;
  int j0 = blockIdx.x * BN;
  int tid = threadIdx.x;
  int tx = tid & 15, ty = tid >> 4;

  float2 acc[4][4];
  #pragma unroll
  for (int r=0;r<4;r++)
    #pragma unroll
    for (int c=0;c<4;c++) acc[r][c] = make_float2(0.f, 0.f);

  for (int kt = 0; kt < K; kt += BK){
    { // A tile: 64 x 16
      int i  = tid >> 2;
      int k0 = (tid & 3) * 4;
      #pragma unroll
      for (int q=0;q<4;q++)
        As[i][k0+q] = A[(long)(i0+i)*lda + kt + k0 + q];
    }
    if (TB == 0){
      #pragma unroll
      for (int r=0;r<4;r++){
        int kk = (tid >> 6) + r*4;
        int j  = tid & 63;
        Bs[kk][j] = B[(long)(kt+kk)*ldb + j0 + j];
      }
    } else {
      int j  = tid >> 2;
      int k0 = (tid & 3) * 4;
      #pragma unroll
      for (int q=0;q<4;q++)
        Bs[k0+q][j] = B[(long)(j0+j)*ldb + kt + k0 + q];
    }
    __syncthreads();

    #pragma unroll
    for (int kk=0;kk<BK;kk++){
      float2 a[4], bv[4];
      #pragma unroll
      for (int r=0;r<4;r++) a[r] = As[ty + r*16][kk];
      #pragma unroll
      for (int c=0;c<4;c++) bv[c] = Bs[kk][tx + c*16];
      #pragma unroll
      for (int r=0;r<4;r++)
        #pragma unroll
        for (int c=0;c<4;c++){
          acc[r][c].x = fmaf(a[r].x, bv[c].x, fmaf(-a[r].y, bv[c].y, acc[r][c].x));
          acc[r][c].y = fmaf(a[r].x, bv[c].y, fmaf( a[r].y, bv[c].x, acc[r][c].y));
        }
    }
    __syncthreads();
  }

  #pragma unroll
  for (int r=0;r<4;r++)
    #pragma unroll
    for (int c=0;c<4;c++){
      int i = i0 + ty + r*16;
      int j = j0 + tx + c*16;
      C[(long)i*ldc + j] = acc[r][c];
    }
}

// ---------- per-slice mean/std (ddof=1) ----------
__global__ void stats_k(const float2* __restrict__ img, float4* __restrict__ stats){
  int b = blockIdx.x;
  const float2* p = img + (long)b * (HH*HH);
  double sr=0.0, si=0.0, srr=0.0, sii=0.0;
  for (int i = threadIdx.x; i < HH*HH; i += 256){
    float2 v = p[i];
    sr += (double)v.x; si += (double)v.y;
    srr += (double)v.x*(double)v.x; sii += (double)v.y*(double)v.y;
  }
  __shared__ double sh[256];
  double vals[4] = {sr, si, srr, sii};
  double red[4];
  #pragma unroll
  for (int q=0;q<4;q++){
    sh[threadIdx.x] = vals[q];
    __syncthreads();
    for (int s=128; s>0; s>>=1){
      if (threadIdx.x < s) sh[threadIdx.x] += sh[threadIdx.x + s];
      __syncthreads();
    }
    red[q] = sh[0];
    __syncthreads();
  }
  if (threadIdx.x == 0){
    double N = (double)(HH*HH);
    double mr = red[0]/N, mi = red[1]/N;
    double vr = (red[2] - N*mr*mr)/(N-1.0);
    double vi = (red[3] - N*mi*mi)/(N-1.0);
    stats[b] = make_float4((float)mr, (float)mi,
                           (float)(1.0/sqrt(vr)), (float)(1.0/sqrt(vi)));
  }
}

// ---------- normalization + apodization divide (in-place safe) ----------
__global__ void norm_apod(const float2* __restrict__ img, const float4* __restrict__ stats,
                          const float* __restrict__ rap, float2* __restrict__ xn){
  int idx = blockIdx.x*256 + threadIdx.x;  // 8*320*320
  if (idx >= NB*HH*HH) return;
  int b = idx / (HH*HH), rem = idx - b*(HH*HH);
  int i = rem / HH, j = rem - i*HH;
  float4 st = stats[b];
  float2 v = img[idx];
  float sc = rap[i]*rap[j];
  xn[idx] = make_float2((v.x - st.x)*st.z*sc, (v.y - st.y)*st.w*sc);
}

// ---------- KB interpolation gather: ONE slice ----------
// Xos1: 640x640 row-major complex (float2). Output mode by cplx flag.
__global__ __launch_bounds__(256)
void interp1(const float* __restrict__ tkx, const float* __restrict__ tky,
             const float2* __restrict__ Xos1, float* __restrict__ out,
             int slice, int cplx, float beta, float inv_i0b){
  int p = blockIdx.x*256 + threadIdx.x;   // 512000 points
  if (p >= PTS) return;
  float gx = tkx[p]*2.0f, gy = tky[p]*2.0f;
  int ix0 = (int)floorf(gx) - 2;
  int iy0 = (int)floorf(gy) - 2;
  float wx[6], wy[6]; int ixm[6], iym[6];
  #pragma unroll
  for (int j=0;j<6;j++){
    wx[j] = kbw(gx - (float)(ix0+j), beta, inv_i0b);
    wy[j] = kbw(gy - (float)(iy0+j), beta, inv_i0b);
    int ix = (ix0+j) % GG; if (ix < 0) ix += GG; ixm[j] = ix;
    int iy = (iy0+j) % GG; if (iy < 0) iy += GG; iym[j] = iy;
  }
  float ar = 0.f, ai = 0.f;
  #pragma unroll
  for (int jx=0;jx<6;jx++){
    const float2* rowp = Xos1 + (long)ixm[jx]*GG;
    #pragma unroll
    for (int jy=0;jy<6;jy++){
      float w = wx[jx]*wy[jy];
      float2 v = rowp[iym[jy]];
      ar = fmaf(w, v.x, ar);
      ai = fmaf(w, v.y, ai);
    }
  }
  if (cplx){
    ((float2*)out)[(long)slice*PTS + p] = make_float2(ar, ai);
  } else {
    out[(long)slice*PTS + p] = ar;
  }
}

// ---------- launch ----------
extern "C" void kernel_launch(void* const* d_in, const int* in_sizes, int n_in,
                              void* d_out, int out_size, void* d_ws, size_t ws_size,
                              hipStream_t stream) {
  const float* kr  = (const float*)d_in[0];
  const float* ki  = (const float*)d_in[1];
  const float* tkx = (const float*)d_in[2];
  const float* tky = (const float*)d_in[3];
  char* ws = (char*)d_ws;

  // ---- workspace layout: total 15,566,208 B (proven safe: round-2 guard passed) ----
  float2* M1    = (float2*)(ws + 0);          //   819,200 B
  float2* W2    = (float2*)(ws + 819200);     // 1,638,400 B -> 2,457,600
  float*  rap   = (float*) (ws + 2457600);    //     1,280 B -> 2,458,880
  float4* stats = (float4*)(ws + 2458880);    //       128 B -> 2,459,008
  float2* P     = (float2*)(ws + 2459008);    // 6,553,600 B -> 9,012,608  (Kc -> image -> xn)
  float2* Q     = (float2*)(ws + 9012608);    // 6,553,600 B -> 15,566,208 (Trow; then U1+Xos1)
  float2* U1    = Q;                                      // 1,638,400 B (640x320)
  float2* Xos1  = (float2*)(ws + 9012608 + 1638400);      // 3,276,800 B (640x640)
  if (ws_size < (size_t)15566208) return;     // fail clean, don't fault

  int cplx = (out_size >= 8192000) ? 1 : 0;   // complex-interleaved vs real-only output

  // host-side constants (pure CPU math; graph-capture safe)
  double beta_d = M_PI * sqrt(9.0*2.25 - 0.8);
  double qq = beta_d*beta_d/4.0, term = 1.0, i0b = 1.0;
  for (int k=1;k<64;k++){ term *= qq/((double)k*(double)k); i0b += term; }
  float beta = (float)beta_d;
  float inv_i0b = (float)(1.0/i0b);

  build_m1 <<<400, 256, 0, stream>>>(M1);
  build_w2 <<<800, 256, 0, stream>>>(W2);
  build_rap<<<1,   320, 0, stream>>>(rap, beta);
  pack_c   <<<3200,256, 0, stream>>>(kr, ki, P, NB*HH*HH);

  // Q[b] = Kc[b] (320x320) * M1^T     (transform along ky)
  cgemm<1><<<dim3(5,5,NB), 256, 0, stream>>>(P,320,102400, M1,320,0,
                                             Q,320,102400, 320,320,320);
  // P[b] = M1 * Q[b]                  (transform along kx; Kc dead)
  cgemm<0><<<dim3(5,5,NB), 256, 0, stream>>>(M1,320,0, Q,320,102400,
                                             P,320,102400, 320,320,320);
  stats_k  <<<NB, 256, 0, stream>>>(P, stats);
  norm_apod<<<3200,256,0, stream>>>(P, stats, rap, P);   // in-place elementwise

  // per-slice oversampled DFT + gather (Q region reused as U1 + Xos1)
  for (int s = 0; s < NB; ++s){
    // U1 = W2 (640x320) * xn[s] (320x320)
    cgemm<0><<<dim3(5,10,1), 256, 0, stream>>>(W2,320,0, P + (long)s*102400,320,0,
                                               U1,320,0, 640,320,320);
    // Xos1[kx,ky] = sum_my U1[kx,my] * W2[ky,my]
    cgemm<1><<<dim3(10,10,1), 256, 0, stream>>>(U1,320,0, W2,320,0,
                                                Xos1,640,0, 640,640,320);
    interp1<<<2000, 256, 0, stream>>>(tkx, tky, Xos1, (float*)d_out,
                                      s, cplx, beta, inv_i0b);
  }
}

// Round 5
// 626.019 us; speedup vs baseline: 2.0737x; 2.0737x over previous
//
#include <hip/hip_runtime.h>
#include <math.h>

#ifndef M_PI
#define M_PI 3.14159265358979323846
#endif

// ---------- constants ----------
#define HH   320
#define GG   640
#define NB   8
#define PTS  512000   // 800 * 640

// ---------- helpers ----------
__device__ __forceinline__ float bessel_i0f(float x){
  if (x < 3.75f){
    float t = (x*x) * (1.0f/(3.75f*3.75f));
    return 1.0f + t*(3.5156229f + t*(3.0899424f + t*(1.2067492f +
                 t*(0.2659732f + t*(0.0360768f + t*0.0045813f)))));
  } else {
    float t = 3.75f/x;
    float p = 0.39894228f + t*(0.01328592f + t*(0.00225319f + t*(-0.00157565f +
              t*(0.00916281f + t*(-0.02057706f + t*(0.02635537f +
              t*(-0.01647633f + t*0.00392377f)))))));
    return expf(x)*rsqrtf(x)*p;
  }
}

__device__ __forceinline__ float kbw(float d, float beta, float inv_i0b){
  float q = d * 0.33333333333333f;        // 2d/W with W=6
  float u = 1.0f - q*q;
  u = fmaxf(u, 0.0f);
  return bessel_i0f(beta * sqrtf(u)) * inv_i0b;
}

// ---------- build DFT matrices ----------
// M1[x,k] = (1/sqrt(320)) * (-1)^(x+k) * exp(+2*pi*i*x*k/320)
__global__ void build_m1(float2* __restrict__ M1){
  int idx = blockIdx.x*256 + threadIdx.x;
  if (idx >= HH*HH) return;
  int x = idx / HH, k = idx - x*HH;
  int r = (x*k) % HH;
  float ang = (float)r * (6.283185307179586f/(float)HH);
  float s, c; sincosf(ang, &s, &c);
  float sg = ((x + k) & 1) ? -0.05590169943749474f : 0.05590169943749474f;
  M1[idx] = make_float2(sg*c, sg*s);
}

// W2[k,m] = exp(-2*pi*i*k*(m-160)/640)   (640 x 320)
__global__ void build_w2(float2* __restrict__ W2){
  int idx = blockIdx.x*256 + threadIdx.x;
  if (idx >= GG*HH) return;
  int k = idx / HH, m = idx - k*HH;
  int t = (k * (m - 160)) % GG; if (t < 0) t += GG;
  float ang = (float)t * (6.283185307179586f/(float)GG);
  float s, c; sincosf(ang, &s, &c);
  W2[idx] = make_float2(c, -s);
}

// rap[n] = 1 / apod1d(n)
__global__ void build_rap(float* __restrict__ rap, float beta){
  int n = threadIdx.x;  // 320 threads
  if (n >= HH) return;
  float f = (float)(n - 160) * (1.0f/(float)GG);
  float w = 3.14159265358979f * 6.0f * f;
  float t = beta*beta - w*w;
  float z = fmaxf(sqrtf(fabsf(t)), 1e-7f);
  float a = (t > 0.0f ? sinhf(z) : sinf(z)) / z;
  float a0 = sinhf(beta) / beta;
  rap[n] = a0 / a;
}

// ---------- pack two real arrays into interleaved complex ----------
__global__ void pack_c(const float* __restrict__ re, const float* __restrict__ im,
                       float2* __restrict__ out, int n){
  int i = blockIdx.x*256 + threadIdx.x;
  if (i < n) out[i] = make_float2(re[i], im[i]);
}

// ---------- batched complex GEMM ----------
// TB=0 (NN): C[i,j] = sum_k A[i,k]*B[k,j]
// TB=1 (NT): C[i,j] = sum_k A[i,k]*B[j,k]
// C element addr: C + b*cbatch + (i*ldc + j)*cstride    (float2 units)
#define BM 64
#define BN 64
#define BK 16

template<int TB>
__global__ __launch_bounds__(256)
void cgemm(const float2* __restrict__ A, int lda, long abatch,
           const float2* __restrict__ B, int ldb, long bbatch,
           float2* __restrict__ C, int ldc, int cstride, long cbatch,
           int M, int N, int K)
{
  __shared__ float2 As[BM][BK+1];
  __shared__ float2 Bs[BK][BN+1];
  int b = blockIdx.z;
  A += (long)b * abatch;
  B += (long)b * bbatch;
  C += (long)b * cbatch;
  int i0 = blockIdx.y * BM;
  int j0 = blockIdx.x * BN;
  int tid = threadIdx.x;
  int tx = tid & 15, ty = tid >> 4;

  float2 acc[4][4];
  #pragma unroll
  for (int r=0;r<4;r++)
    #pragma unroll
    for (int c=0;c<4;c++) acc[r][c] = make_float2(0.f, 0.f);

  for (int kt = 0; kt < K; kt += BK){
    { // A tile: 64 x 16
      int i  = tid >> 2;
      int k0 = (tid & 3) * 4;
      #pragma unroll
      for (int q=0;q<4;q++)
        As[i][k0+q] = A[(long)(i0+i)*lda + kt + k0 + q];
    }
    if (TB == 0){
      #pragma unroll
      for (int r=0;r<4;r++){
        int kk = (tid >> 6) + r*4;
        int j  = tid & 63;
        Bs[kk][j] = B[(long)(kt+kk)*ldb + j0 + j];
      }
    } else {
      int j  = tid >> 2;
      int k0 = (tid & 3) * 4;
      #pragma unroll
      for (int q=0;q<4;q++)
        Bs[k0+q][j] = B[(long)(j0+j)*ldb + kt + k0 + q];
    }
    __syncthreads();

    #pragma unroll
    for (int kk=0;kk<BK;kk++){
      float2 a[4], bv[4];
      #pragma unroll
      for (int r=0;r<4;r++) a[r] = As[ty + r*16][kk];
      #pragma unroll
      for (int c=0;c<4;c++) bv[c] = Bs[kk][tx + c*16];
      #pragma unroll
      for (int r=0;r<4;r++)
        #pragma unroll
        for (int c=0;c<4;c++){
          acc[r][c].x = fmaf(a[r].x, bv[c].x, fmaf(-a[r].y, bv[c].y, acc[r][c].x));
          acc[r][c].y = fmaf(a[r].x, bv[c].y, fmaf( a[r].y, bv[c].x, acc[r][c].y));
        }
    }
    __syncthreads();
  }

  #pragma unroll
  for (int r=0;r<4;r++)
    #pragma unroll
    for (int c=0;c<4;c++){
      int i = i0 + ty + r*16;
      int j = j0 + tx + c*16;
      C[((long)i*ldc + j)*(long)cstride] = acc[r][c];
    }
}

// ---------- per-slice mean/std, stage 1: 32 segments/slice partial sums ----------
__global__ void stats_part(const float2* __restrict__ img, double* __restrict__ part){
  int slice = blockIdx.y, seg = blockIdx.x;   // 8 x 32
  const float2* p = img + (long)slice*(HH*HH) + (long)seg*3200;
  double sr=0.0, si=0.0, srr=0.0, sii=0.0;
  for (int i = threadIdx.x; i < 3200; i += 256){
    float2 v = p[i];
    sr += (double)v.x; si += (double)v.y;
    srr += (double)v.x*(double)v.x; sii += (double)v.y*(double)v.y;
  }
  __shared__ double sh[256];
  double vals[4] = {sr, si, srr, sii};
  #pragma unroll
  for (int q=0;q<4;q++){
    sh[threadIdx.x] = vals[q];
    __syncthreads();
    for (int s=128; s>0; s>>=1){
      if (threadIdx.x < s) sh[threadIdx.x] += sh[threadIdx.x + s];
      __syncthreads();
    }
    if (threadIdx.x == 0) part[((long)slice*32 + seg)*4 + q] = sh[0];
    __syncthreads();
  }
}

// ---------- stage 2: finish (ddof=1) ----------
__global__ void stats_fin(const double* __restrict__ part, float4* __restrict__ stats){
  int b = blockIdx.x;
  int t = threadIdx.x;  // 64
  __shared__ double sh[64];
  double red[4];
  #pragma unroll
  for (int q=0;q<4;q++){
    sh[t] = (t < 32) ? part[((long)b*32 + t)*4 + q] : 0.0;
    __syncthreads();
    for (int s=32; s>0; s>>=1){
      if (t < s) sh[t] += sh[t + s];
      __syncthreads();
    }
    red[q] = sh[0];
    __syncthreads();
  }
  if (t == 0){
    double N = (double)(HH*HH);
    double mr = red[0]/N, mi = red[1]/N;
    double vr = (red[2] - N*mr*mr)/(N-1.0);
    double vi = (red[3] - N*mi*mi)/(N-1.0);
    stats[b] = make_float4((float)mr, (float)mi,
                           (float)(1.0/sqrt(vr)), (float)(1.0/sqrt(vi)));
  }
}

// ---------- normalization + apodization divide (in-place) ----------
__global__ void norm_apod(const float2* img, const float4* __restrict__ stats,
                          const float* __restrict__ rap, float2* xn){
  int idx = blockIdx.x*256 + threadIdx.x;  // 8*320*320
  if (idx >= NB*HH*HH) return;
  int b = idx / (HH*HH), rem = idx - b*(HH*HH);
  int i = rem / HH, j = rem - i*HH;
  float4 st = stats[b];
  float2 v = img[idx];
  float sc = rap[i]*rap[j];
  xn[idx] = make_float2((v.x - st.x)*st.z*sc, (v.y - st.y)*st.w*sc);
}

// ---------- KB interpolation gather: NC interleaved slices ----------
// Xos layout: [kx][ky][NC] float2
template<int NC>
__global__ __launch_bounds__(256)
void interpN(const float* __restrict__ tkx, const float* __restrict__ tky,
             const float2* __restrict__ Xos, float* __restrict__ out,
             int slice0, int cplx, float beta, float inv_i0b){
  int p = blockIdx.x*256 + threadIdx.x;   // 512000 points
  if (p >= PTS) return;
  float gx = tkx[p]*2.0f, gy = tky[p]*2.0f;
  int ix0 = (int)floorf(gx) - 2;
  int iy0 = (int)floorf(gy) - 2;
  float wx[6], wy[6]; int ixm[6], iym[6];
  #pragma unroll
  for (int j=0;j<6;j++){
    wx[j] = kbw(gx - (float)(ix0+j), beta, inv_i0b);
    wy[j] = kbw(gy - (float)(iy0+j), beta, inv_i0b);
    int ix = (ix0+j) % GG; if (ix < 0) ix += GG; ixm[j] = ix;
    int iy = (iy0+j) % GG; if (iy < 0) iy += GG; iym[j] = iy;
  }
  float2 acc[NC];
  #pragma unroll
  for (int s=0;s<NC;s++) acc[s] = make_float2(0.f, 0.f);

  #pragma unroll
  for (int jx=0;jx<6;jx++){
    const float2* rowp = Xos + (long)ixm[jx]*(GG*NC);
    #pragma unroll
    for (int jy=0;jy<6;jy++){
      float w = wx[jx]*wy[jy];
      const float2* s2 = rowp + iym[jy]*NC;
      if (NC % 2 == 0){
        const float4* s4 = (const float4*)s2;
        #pragma unroll
        for (int q=0;q<NC/2;q++){
          float4 v = s4[q];
          acc[2*q  ].x = fmaf(w, v.x, acc[2*q  ].x);
          acc[2*q  ].y = fmaf(w, v.y, acc[2*q  ].y);
          acc[2*q+1].x = fmaf(w, v.z, acc[2*q+1].x);
          acc[2*q+1].y = fmaf(w, v.w, acc[2*q+1].y);
        }
      } else {
        float2 v = s2[0];
        acc[0].x = fmaf(w, v.x, acc[0].x);
        acc[0].y = fmaf(w, v.y, acc[0].y);
      }
    }
  }
  if (cplx){
    float2* o2 = (float2*)out;
    #pragma unroll
    for (int s=0;s<NC;s++) o2[(long)(slice0+s)*PTS + p] = acc[s];
  } else {
    #pragma unroll
    for (int s=0;s<NC;s++) out[(long)(slice0+s)*PTS + p] = acc[s].x;
  }
}

// ---------- launch ----------
extern "C" void kernel_launch(void* const* d_in, const int* in_sizes, int n_in,
                              void* d_out, int out_size, void* d_ws, size_t ws_size,
                              hipStream_t stream) {
  const float* kr  = (const float*)d_in[0];
  const float* ki  = (const float*)d_in[1];
  const float* tkx = (const float*)d_in[2];
  const float* tky = (const float*)d_in[3];
  char* ws = (char*)d_ws;

  // ---- fixed workspace layout ----
  float2* M1    = (float2*)(ws + 0);          //   819,200 B
  float2* W2    = (float2*)(ws + 819200);     // 1,638,400 B -> 2,457,600
  float*  rap   = (float*) (ws + 2457600);    //     1,280 B -> 2,458,880
  float4* stats = (float4*)(ws + 2458880);    //       128 B -> 2,459,008
  double* part  = (double*)(ws + 2459008);    //     8,192 B -> 2,467,200
  float2* P     = (float2*)(ws + 2467200);    // 6,553,600 B -> 9,020,800  (Kc -> image -> xn)
  float2* Q     = (float2*)(ws + 9020800);    // 6,553,600 B (Trow; dead after GEMM2)
  const long base = 9020800;

  // ---- choose slice chunk size nc from actual ws_size (call-invariant) ----
  int nc = 1;
  if      (ws_size >= (size_t)(base + 8L*4915200)) nc = 8;   // 48,342,400
  else if (ws_size >= (size_t)(base + 4L*4915200)) nc = 4;   // 28,681,600
  else if (ws_size >= (size_t)(base + 2L*4915200)) nc = 2;   // 18,851,200
  if (ws_size < (size_t)(base + 4915200)) return;            // < 13.94 MB: fail clean

  float2* U   = (float2*)(ws + base);                        // nc * 1,638,400 B
  float2* Xos = (float2*)(ws + base + (long)nc*1638400);     // nc * 3,276,800 B

  int cplx = (out_size >= 8192000) ? 1 : 0;

  // host-side constants (pure CPU math; graph-capture safe)
  double beta_d = M_PI * sqrt(9.0*2.25 - 0.8);
  double qq = beta_d*beta_d/4.0, term = 1.0, i0b = 1.0;
  for (int k=1;k<64;k++){ term *= qq/((double)k*(double)k); i0b += term; }
  float beta = (float)beta_d;
  float inv_i0b = (float)(1.0/i0b);

  build_m1 <<<400, 256, 0, stream>>>(M1);
  build_w2 <<<800, 256, 0, stream>>>(W2);
  build_rap<<<1,   320, 0, stream>>>(rap, beta);
  pack_c   <<<3200,256, 0, stream>>>(kr, ki, P, NB*HH*HH);

  // Q[b] = Kc[b] (320x320) * M1^T     (transform along ky)
  cgemm<1><<<dim3(5,5,NB), 256, 0, stream>>>(P,320,102400, M1,320,0,
                                             Q,320,1,102400, 320,320,320);
  // P[b] = M1 * Q[b]                  (transform along kx; Kc dead)
  cgemm<0><<<dim3(5,5,NB), 256, 0, stream>>>(M1,320,0, Q,320,102400,
                                             P,320,1,102400, 320,320,320);
  stats_part<<<dim3(32,NB), 256, 0, stream>>>(P, part);
  stats_fin <<<NB, 64, 0, stream>>>(part, stats);
  norm_apod <<<3200, 256, 0, stream>>>(P, stats, rap, P);   // in-place

  // oversampled DFT + gather, nc slices per chunk (U/Xos overlay Q region)
  for (int c = 0; c < NB/nc; ++c){
    // U[s] = W2 (640x320) * xn[c*nc+s] (320x320)
    cgemm<0><<<dim3(5,10,nc), 256, 0, stream>>>(W2,320,0, P + (long)c*nc*102400,320,102400,
                                                U,320,1,204800, 640,320,320);
    // Xos[kx][ky][s] = sum_my U[s,kx,my] * W2[ky,my]
    cgemm<1><<<dim3(10,10,nc), 256, 0, stream>>>(U,320,204800, W2,320,0,
                                                 Xos,640,nc,1, 640,640,320);
    switch (nc){
      case 8: interpN<8><<<2000,256,0,stream>>>(tkx,tky,Xos,(float*)d_out, c*8, cplx, beta, inv_i0b); break;
      case 4: interpN<4><<<2000,256,0,stream>>>(tkx,tky,Xos,(float*)d_out, c*4, cplx, beta, inv_i0b); break;
      case 2: interpN<2><<<2000,256,0,stream>>>(tkx,tky,Xos,(float*)d_out, c*2, cplx, beta, inv_i0b); break;
      default: interpN<1><<<2000,256,0,stream>>>(tkx,tky,Xos,(float*)d_out, c,   cplx, beta, inv_i0b); break;
    }
  }
}

// Round 6
// 522.787 us; speedup vs baseline: 2.4832x; 1.1975x over previous
//
#include <hip/hip_runtime.h>
#include <math.h>

#ifndef M_PI
#define M_PI 3.14159265358979323846
#endif

// ---------- constants ----------
#define HH   320
#define GG   640
#define NB   8
#define PTS  512000   // 800 * 640

// ---------- helpers ----------
__device__ __forceinline__ float bessel_i0f(float x){
  if (x < 3.75f){
    float t = (x*x) * (1.0f/(3.75f*3.75f));
    return 1.0f + t*(3.5156229f + t*(3.0899424f + t*(1.2067492f +
                 t*(0.2659732f + t*(0.0360768f + t*0.0045813f)))));
  } else {
    float t = 3.75f/x;
    float p = 0.39894228f + t*(0.01328592f + t*(0.00225319f + t*(-0.00157565f +
              t*(0.00916281f + t*(-0.02057706f + t*(0.02635537f +
              t*(-0.01647633f + t*0.00392377f)))))));
    return expf(x)*rsqrtf(x)*p;
  }
}

__device__ __forceinline__ float kbw(float d, float beta, float inv_i0b){
  float q = d * 0.33333333333333f;        // 2d/W with W=6
  float u = 1.0f - q*q;
  u = fmaxf(u, 0.0f);
  return bessel_i0f(beta * sqrtf(u)) * inv_i0b;
}

// ---------- build DFT matrices ----------
// M1[x,k] = (1/sqrt(320)) * (-1)^(x+k) * exp(+2*pi*i*x*k/320)
__global__ void build_m1(float2* __restrict__ M1){
  int idx = blockIdx.x*256 + threadIdx.x;
  if (idx >= HH*HH) return;
  int x = idx / HH, k = idx - x*HH;
  int r = (x*k) % HH;
  float ang = (float)r * (6.283185307179586f/(float)HH);
  float s, c; sincosf(ang, &s, &c);
  float sg = ((x + k) & 1) ? -0.05590169943749474f : 0.05590169943749474f;
  M1[idx] = make_float2(sg*c, sg*s);
}

// W2[k,m] = exp(-2*pi*i*k*(m-160)/640)   (640 x 320)
__global__ void build_w2(float2* __restrict__ W2){
  int idx = blockIdx.x*256 + threadIdx.x;
  if (idx >= GG*HH) return;
  int k = idx / HH, m = idx - k*HH;
  int t = (k * (m - 160)) % GG; if (t < 0) t += GG;
  float ang = (float)t * (6.283185307179586f/(float)GG);
  float s, c; sincosf(ang, &s, &c);
  W2[idx] = make_float2(c, -s);
}

// rap[n] = 1 / apod1d(n)
__global__ void build_rap(float* __restrict__ rap, float beta){
  int n = threadIdx.x;  // 320 threads
  if (n >= HH) return;
  float f = (float)(n - 160) * (1.0f/(float)GG);
  float w = 3.14159265358979f * 6.0f * f;
  float t = beta*beta - w*w;
  float z = fmaxf(sqrtf(fabsf(t)), 1e-7f);
  float a = (t > 0.0f ? sinhf(z) : sinf(z)) / z;
  float a0 = sinhf(beta) / beta;
  rap[n] = a0 / a;
}

// ---------- pack two real arrays into interleaved complex ----------
__global__ void pack_c(const float* __restrict__ re, const float* __restrict__ im,
                       float2* __restrict__ out, int n){
  int i = blockIdx.x*256 + threadIdx.x;
  if (i < n) out[i] = make_float2(re[i], im[i]);
}

// ---------- batched complex GEMM ----------
// TB=0 (NN): C[i,j] = sum_k A[i,k]*B[k,j]
// TB=1 (NT): C[i,j] = sum_k A[i,k]*B[j,k]
// C element addr: C + b*cbatch + (i*ldc + j)*cstride    (float2 units)
#define BM 64
#define BN 64
#define BK 16

template<int TB>
__global__ __launch_bounds__(256)
void cgemm(const float2* __restrict__ A, int lda, long abatch,
           const float2* __restrict__ B, int ldb, long bbatch,
           float2* __restrict__ C, int ldc, int cstride, long cbatch,
           int M, int N, int K)
{
  __shared__ float2 As[BM][BK+1];
  __shared__ float2 Bs[BK][BN+1];
  int b = blockIdx.z;
  A += (long)b * abatch;
  B += (long)b * bbatch;
  C += (long)b * cbatch;
  int i0 = blockIdx.y * BM;
  int j0 = blockIdx.x * BN;
  int tid = threadIdx.x;
  int tx = tid & 15, ty = tid >> 4;

  float2 acc[4][4];
  #pragma unroll
  for (int r=0;r<4;r++)
    #pragma unroll
    for (int c=0;c<4;c++) acc[r][c] = make_float2(0.f, 0.f);

  for (int kt = 0; kt < K; kt += BK){
    { // A tile: 64 x 16
      int i  = tid >> 2;
      int k0 = (tid & 3) * 4;
      #pragma unroll
      for (int q=0;q<4;q++)
        As[i][k0+q] = A[(long)(i0+i)*lda + kt + k0 + q];
    }
    if (TB == 0){
      #pragma unroll
      for (int r=0;r<4;r++){
        int kk = (tid >> 6) + r*4;
        int j  = tid & 63;
        Bs[kk][j] = B[(long)(kt+kk)*ldb + j0 + j];
      }
    } else {
      int j  = tid >> 2;
      int k0 = (tid & 3) * 4;
      #pragma unroll
      for (int q=0;q<4;q++)
        Bs[k0+q][j] = B[(long)(j0+j)*ldb + kt + k0 + q];
    }
    __syncthreads();

    #pragma unroll
    for (int kk=0;kk<BK;kk++){
      float2 a[4], bv[4];
      #pragma unroll
      for (int r=0;r<4;r++) a[r] = As[ty + r*16][kk];
      #pragma unroll
      for (int c=0;c<4;c++) bv[c] = Bs[kk][tx + c*16];
      #pragma unroll
      for (int r=0;r<4;r++)
        #pragma unroll
        for (int c=0;c<4;c++){
          acc[r][c].x = fmaf(a[r].x, bv[c].x, fmaf(-a[r].y, bv[c].y, acc[r][c].x));
          acc[r][c].y = fmaf(a[r].x, bv[c].y, fmaf( a[r].y, bv[c].x, acc[r][c].y));
        }
    }
    __syncthreads();
  }

  #pragma unroll
  for (int r=0;r<4;r++)
    #pragma unroll
    for (int c=0;c<4;c++){
      int i = i0 + ty + r*16;
      int j = j0 + tx + c*16;
      C[((long)i*ldc + j)*(long)cstride] = acc[r][c];
    }
}

// ---------- per-slice mean/std, stage 1: 32 segments/slice partial sums ----------
__global__ void stats_part(const float2* __restrict__ img, double* __restrict__ part){
  int slice = blockIdx.y, seg = blockIdx.x;   // 8 x 32
  const float2* p = img + (long)slice*(HH*HH) + (long)seg*3200;
  double sr=0.0, si=0.0, srr=0.0, sii=0.0;
  for (int i = threadIdx.x; i < 3200; i += 256){
    float2 v = p[i];
    sr += (double)v.x; si += (double)v.y;
    srr += (double)v.x*(double)v.x; sii += (double)v.y*(double)v.y;
  }
  __shared__ double sh[256];
  double vals[4] = {sr, si, srr, sii};
  #pragma unroll
  for (int q=0;q<4;q++){
    sh[threadIdx.x] = vals[q];
    __syncthreads();
    for (int s=128; s>0; s>>=1){
      if (threadIdx.x < s) sh[threadIdx.x] += sh[threadIdx.x + s];
      __syncthreads();
    }
    if (threadIdx.x == 0) part[((long)slice*32 + seg)*4 + q] = sh[0];
    __syncthreads();
  }
}

// ---------- stage 2: finish (ddof=1) ----------
__global__ void stats_fin(const double* __restrict__ part, float4* __restrict__ stats){
  int b = blockIdx.x;
  int t = threadIdx.x;  // 64
  __shared__ double sh[64];
  double red[4];
  #pragma unroll
  for (int q=0;q<4;q++){
    sh[t] = (t < 32) ? part[((long)b*32 + t)*4 + q] : 0.0;
    __syncthreads();
    for (int s=32; s>0; s>>=1){
      if (t < s) sh[t] += sh[t + s];
      __syncthreads();
    }
    red[q] = sh[0];
    __syncthreads();
  }
  if (t == 0){
    double N = (double)(HH*HH);
    double mr = red[0]/N, mi = red[1]/N;
    double vr = (red[2] - N*mr*mr)/(N-1.0);
    double vi = (red[3] - N*mi*mi)/(N-1.0);
    stats[b] = make_float4((float)mr, (float)mi,
                           (float)(1.0/sqrt(vr)), (float)(1.0/sqrt(vi)));
  }
}

// ---------- normalization + apodization divide (in-place) ----------
__global__ void norm_apod(const float2* img, const float4* __restrict__ stats,
                          const float* __restrict__ rap, float2* xn){
  int idx = blockIdx.x*256 + threadIdx.x;  // 8*320*320
  if (idx >= NB*HH*HH) return;
  int b = idx / (HH*HH), rem = idx - b*(HH*HH);
  int i = rem / HH, j = rem - i*HH;
  float4 st = stats[b];
  float2 v = img[idx];
  float sc = rap[i]*rap[j];
  xn[idx] = make_float2((v.x - st.x)*st.z*sc, (v.y - st.y)*st.w*sc);
}

// ---------- KB interpolation gather, row-split: 6 waves/block, wave = jx row ----------
// Xos layout: [kx][ky][NC] float2. Block = 384 threads = 6 waves x 64 points.
// Wave w handles KB-row jx=w for 64 consecutive points; partials combine in LDS.
template<int NC>
__global__ __launch_bounds__(384)
void interp6(const float* __restrict__ tkx, const float* __restrict__ tky,
             const float2* __restrict__ Xos, float* __restrict__ out,
             int slice0, int cplx, float beta, float inv_i0b){
  __shared__ float2 sh[NC][6][64];
  int tid = threadIdx.x;
  int ptl = tid & 63;          // point within block (lane)
  int jx  = tid >> 6;          // KB row index = wave index
  int p   = blockIdx.x*64 + ptl;   // 8000 blocks * 64 = 512000 exactly

  float gx = tkx[p]*2.0f, gy = tky[p]*2.0f;
  int ix0 = (int)floorf(gx) - 2;
  int iy0 = (int)floorf(gy) - 2;

  int ixu = ix0 + jx;
  int ixm = (ixu < 0) ? ixu + GG : ((ixu >= GG) ? ixu - GG : ixu);
  float wxj = kbw(gx - (float)ixu, beta, inv_i0b);

  float wy[6]; int iym[6];
  #pragma unroll
  for (int j=0;j<6;j++){
    int iyu = iy0 + j;
    wy[j] = kbw(gy - (float)iyu, beta, inv_i0b);
    iym[j] = (iyu < 0) ? iyu + GG : ((iyu >= GG) ? iyu - GG : iyu);
  }

  float2 acc[NC];
  #pragma unroll
  for (int s=0;s<NC;s++) acc[s] = make_float2(0.f, 0.f);

  const float2* rowp = Xos + (long)ixm*(GG*NC);
  #pragma unroll
  for (int jy=0;jy<6;jy++){
    float w = wy[jy];
    const float2* s2 = rowp + iym[jy]*NC;
    if (NC % 2 == 0){
      const float4* s4 = (const float4*)s2;
      #pragma unroll
      for (int q=0;q<NC/2;q++){
        float4 v = s4[q];
        acc[2*q  ].x = fmaf(w, v.x, acc[2*q  ].x);
        acc[2*q  ].y = fmaf(w, v.y, acc[2*q  ].y);
        acc[2*q+1].x = fmaf(w, v.z, acc[2*q+1].x);
        acc[2*q+1].y = fmaf(w, v.w, acc[2*q+1].y);
      }
    } else {
      float2 v = s2[0];
      acc[0].x = fmaf(w, v.x, acc[0].x);
      acc[0].y = fmaf(w, v.y, acc[0].y);
    }
  }
  // scale by this thread's wx and stash partial (conflict-free: lanes contiguous)
  #pragma unroll
  for (int s=0;s<NC;s++)
    sh[s][jx][ptl] = make_float2(acc[s].x*wxj, acc[s].y*wxj);
  __syncthreads();

  // reduce 6 rows per (point, slice); 64*NC reducer threads (loop if > blockDim)
  for (int t2 = tid; t2 < 64*NC; t2 += 384){
    int pt = t2 / NC;
    int s  = t2 - pt*NC;
    float2 r = make_float2(0.f, 0.f);
    #pragma unroll
    for (int j=0;j<6;j++){
      float2 v = sh[s][j][pt];
      r.x += v.x; r.y += v.y;
    }
    long pg = (long)blockIdx.x*64 + pt;
    if (cplx){
      ((float2*)out)[(long)(slice0+s)*PTS + pg] = r;
    } else {
      out[(long)(slice0+s)*PTS + pg] = r.x;
    }
  }
}

// ---------- launch ----------
extern "C" void kernel_launch(void* const* d_in, const int* in_sizes, int n_in,
                              void* d_out, int out_size, void* d_ws, size_t ws_size,
                              hipStream_t stream) {
  const float* kr  = (const float*)d_in[0];
  const float* ki  = (const float*)d_in[1];
  const float* tkx = (const float*)d_in[2];
  const float* tky = (const float*)d_in[3];
  char* ws = (char*)d_ws;

  // ---- fixed workspace layout ----
  float2* M1    = (float2*)(ws + 0);          //   819,200 B
  float2* W2    = (float2*)(ws + 819200);     // 1,638,400 B -> 2,457,600
  float*  rap   = (float*) (ws + 2457600);    //     1,280 B -> 2,458,880
  float4* stats = (float4*)(ws + 2458880);    //       128 B -> 2,459,008
  double* part  = (double*)(ws + 2459008);    //     8,192 B -> 2,467,200
  float2* P     = (float2*)(ws + 2467200);    // 6,553,600 B -> 9,020,800  (Kc -> image -> xn)
  float2* Q     = (float2*)(ws + 9020800);    // 6,553,600 B (Trow; dead after GEMM2)
  const long base = 9020800;

  // ---- choose slice chunk size nc from actual ws_size (call-invariant) ----
  int nc = 1;
  if      (ws_size >= (size_t)(base + 8L*4915200)) nc = 8;   // 48,342,400
  else if (ws_size >= (size_t)(base + 4L*4915200)) nc = 4;   // 28,681,600
  else if (ws_size >= (size_t)(base + 2L*4915200)) nc = 2;   // 18,851,200
  if (ws_size < (size_t)(base + 4915200)) return;            // < 13.94 MB: fail clean

  float2* U   = (float2*)(ws + base);                        // nc * 1,638,400 B
  float2* Xos = (float2*)(ws + base + (long)nc*1638400);     // nc * 3,276,800 B

  int cplx = (out_size >= 8192000) ? 1 : 0;

  // host-side constants (pure CPU math; graph-capture safe)
  double beta_d = M_PI * sqrt(9.0*2.25 - 0.8);
  double qq = beta_d*beta_d/4.0, term = 1.0, i0b = 1.0;
  for (int k=1;k<64;k++){ term *= qq/((double)k*(double)k); i0b += term; }
  float beta = (float)beta_d;
  float inv_i0b = (float)(1.0/i0b);

  build_m1 <<<400, 256, 0, stream>>>(M1);
  build_w2 <<<800, 256, 0, stream>>>(W2);
  build_rap<<<1,   320, 0, stream>>>(rap, beta);
  pack_c   <<<3200,256, 0, stream>>>(kr, ki, P, NB*HH*HH);

  // Q[b] = Kc[b] (320x320) * M1^T     (transform along ky)
  cgemm<1><<<dim3(5,5,NB), 256, 0, stream>>>(P,320,102400, M1,320,0,
                                             Q,320,1,102400, 320,320,320);
  // P[b] = M1 * Q[b]                  (transform along kx; Kc dead)
  cgemm<0><<<dim3(5,5,NB), 256, 0, stream>>>(M1,320,0, Q,320,102400,
                                             P,320,1,102400, 320,320,320);
  stats_part<<<dim3(32,NB), 256, 0, stream>>>(P, part);
  stats_fin <<<NB, 64, 0, stream>>>(part, stats);
  norm_apod <<<3200, 256, 0, stream>>>(P, stats, rap, P);   // in-place

  // oversampled DFT + gather, nc slices per chunk (U/Xos overlay Q region)
  for (int c = 0; c < NB/nc; ++c){
    // U[s] = W2 (640x320) * xn[c*nc+s] (320x320)
    cgemm<0><<<dim3(5,10,nc), 256, 0, stream>>>(W2,320,0, P + (long)c*nc*102400,320,102400,
                                                U,320,1,204800, 640,320,320);
    // Xos[kx][ky][s] = sum_my U[s,kx,my] * W2[ky,my]
    cgemm<1><<<dim3(10,10,nc), 256, 0, stream>>>(U,320,204800, W2,320,0,
                                                 Xos,640,nc,1, 640,640,320);
    switch (nc){
      case 8: interp6<8><<<8000,384,0,stream>>>(tkx,tky,Xos,(float*)d_out, c*8, cplx, beta, inv_i0b); break;
      case 4: interp6<4><<<8000,384,0,stream>>>(tkx,tky,Xos,(float*)d_out, c*4, cplx, beta, inv_i0b); break;
      case 2: interp6<2><<<8000,384,0,stream>>>(tkx,tky,Xos,(float*)d_out, c*2, cplx, beta, inv_i0b); break;
      default: interp6<1><<<8000,384,0,stream>>>(tkx,tky,Xos,(float*)d_out, c,   cplx, beta, inv_i0b); break;
    }
  }
}